// Round 9
// baseline (196.824 us; speedup 1.0000x reference)
//
#include <hip/hip_runtime.h>

#define NB 8192
#define ND 128
#define MARGINF 0.3f
#define FLTMAX 3.402823466e+38f
#define A_TILES 8             // 8 mini-tiles x 16 cols = 128-col cap in scan
#define B_GRID 1024
#define SCALEQ 33554432.0     // 2^25 quantizer -> integer atomics, deterministic

// ws layout (bytes):
//   [0]  uint cnt   [4] uint pd   [16] u64 acc
//   [64]    int   list[8192]
//   [32832] float dapw[8192]
//   [65600] uint  rem[8192]
//   [98368] u64   idxval[8192]   (packed (col<<32)|float_bits; 0xFFFFFFFE = diag)

__device__ __forceinline__ float dot4(float4 x, float4 y) {
    return x.x * y.x + x.y * y.y + x.z * y.z + x.w * y.w;
}

// Butterfly sum within each 32-lane half.
__device__ __forceinline__ float half_reduce(float v) {
    v += __shfl_xor(v, 1, 64);
    v += __shfl_xor(v, 2, 64);
    v += __shfl_xor(v, 4, 64);
    v += __shfl_xor(v, 8, 64);
    v += __shfl_xor(v, 16, 64);
    return v;
}

// Lane owning local column c: col(L) = 2*(L&31) + (L>>5).
__device__ __forceinline__ int owner(int c) {
    return (c & 1) ? 32 + (c >> 1) : (c >> 1);
}

__device__ __forceinline__ int first_col_from_mask(unsigned long long mask) {
    const unsigned int lo = (unsigned int)mask;          // even local cols
    const unsigned int hi = (unsigned int)(mask >> 32);  // odd local cols
    const int ce = lo ? 2 * (__ffs(lo) - 1)     : 0x7fffffff;
    const int co = hi ? 2 * (__ffs(hi) - 1) + 1 : 0x7fffffff;
    return ce < co ? ce : co;
}

__global__ void init_ws(unsigned int* __restrict__ hdr) {
    if (threadIdx.x == 0) {
        hdr[0] = 0u;                              // cnt
        hdr[1] = 0u;                              // pd (pairs done)
        *(unsigned long long*)(hdr + 4) = 0ULL;   // acc (offset 16)
    }
}

// Phase A: one row per wave, scan cols [0,128) in 16-col mini-tiles, early exit.
__global__ __launch_bounds__(256) void triplet_scan(const float* __restrict__ a,
                                                    const float* __restrict__ p,
                                                    const float* __restrict__ n,
                                                    unsigned int* __restrict__ cnt,
                                                    unsigned long long* __restrict__ acc,
                                                    int* __restrict__ list,
                                                    float* __restrict__ dapw,
                                                    unsigned int* __restrict__ rem,
                                                    unsigned long long* __restrict__ idxval) {
    __shared__ float s_part[4];
    const int tid  = threadIdx.x;
    const int wave = tid >> 6;
    const int lane = tid & 63;
    const int q    = lane & 31;
    const int h    = lane >> 5;
    const int row  = blockIdx.x * 4 + wave;

    const float4 a4 = *(const float4*)(a + (size_t)row * ND + q * 4);
    const float4 p4 = *(const float4*)(p + (size_t)row * ND + q * 4);
    const float dist_ap = half_reduce(dot4(a4, p4));
    const float thresh  = dist_ap + MARGINF;

    float lsum = 0.f;
    bool resolved = false;
    for (int t = 0; t < A_TILES && !resolved; ++t) {
        float myval = FLTMAX;
        #pragma unroll
        for (int k = 0; k < 8; ++k) {
            const int col = t * 16 + 2 * k + h;
            const float4 nv = *(const float4*)(n + (size_t)col * ND + q * 4);
            const float v = half_reduce(dot4(a4, nv));
            if (q == k) myval = v;
        }
        const unsigned long long mask = __ballot(myval < thresh);
        if (mask) {  // wave-uniform
            const int c = first_col_from_mask(mask);
            const float dist_an = __shfl(myval, owner(c), 64);
            const float l = dist_an - dist_ap + MARGINF;
            lsum = l > 0.f ? l : 0.f;
            resolved = true;
        }
    }
    if (!resolved && lane == 0) {                 // push to worklist
        const unsigned int k = atomicAdd(cnt, 1u);
        list[k]   = row;
        dapw[k]   = dist_ap;
        idxval[k] = ~0ULL;
        rem[k]    = 128u;
    }
    if (lane == 0) s_part[wave] = lsum;
    __syncthreads();
    if (tid == 0) {
        const double bs = (double)s_part[0] + (double)s_part[1]
                        + (double)s_part[2] + (double)s_part[3];
        if (bs > 0.0) atomicAdd(acc, (unsigned long long)llrint(bs * SCALEQ));
    }
}

// Phase B: (worklist row, 64-col chunk) pairs, one per wave-iter.
// Last pair (pairs-done counter) writes the final mean.
__global__ __launch_bounds__(256) void triplet_cols(const float* __restrict__ a,
                                                    const float* __restrict__ n,
                                                    const unsigned int* __restrict__ cnt,
                                                    unsigned int* __restrict__ pd,
                                                    unsigned long long* __restrict__ acc,
                                                    const int* __restrict__ list,
                                                    const float* __restrict__ dapw,
                                                    unsigned int* __restrict__ rem,
                                                    unsigned long long* __restrict__ idxval,
                                                    float* __restrict__ out) {
    const int tid  = threadIdx.x;
    const int wave = tid >> 6;
    const int lane = tid & 63;
    const int q    = lane & 31;
    const int h    = lane >> 5;
    const int gw   = blockIdx.x * 4 + wave;
    const int C    = (int)*cnt;
    const int npairs = C * 128;

    if (npairs == 0) {                            // degenerate: everything resolved
        if (blockIdx.x == 0 && tid == 0) {
            const unsigned long long s = atomicAdd(acc, 0ULL);
            out[0] = (float)((double)s / SCALEQ / (double)NB);
        }
        return;
    }

    for (int pair = gw; pair < npairs; pair += B_GRID * 4) {
        const int w   = pair >> 7;
        const int tb  = (pair & 127) << 6;
        const int row = list[w];
        const float th = dapw[w] + MARGINF;
        const float4 a4 = *(const float4*)(a + (size_t)row * ND + q * 4);
        float myval = FLTMAX;
        #pragma unroll
        for (int k = 0; k < 32; ++k) {
            const int col = tb + 2 * k + h;
            const float4 nv = *(const float4*)(n + (size_t)col * ND + q * 4);
            const float v = half_reduce(dot4(a4, nv));   // bit-identical to scan
            if (q == k) myval = v;
        }
        if (row >= tb && row < tb + 64) {                // diag fallback candidate
            const float dv = __shfl(myval, owner(row - tb), 64);
            if (lane == 0) {
                const unsigned long long dkey =
                    (0xFFFFFFFEULL << 32) | (unsigned long long)__float_as_uint(dv);
                atomicMin(&idxval[w], dkey);
            }
        }
        const unsigned long long mask = __ballot(myval < th);
        if (mask) {
            const int c = first_col_from_mask(mask);
            const float fv = __shfl(myval, owner(c), 64);
            if (lane == 0) {
                const unsigned long long key =
                    ((unsigned long long)(tb + c) << 32) | (unsigned long long)__float_as_uint(fv);
                atomicMin(&idxval[w], key);              // min col wins
            }
        }
        if (lane == 0) {
            const unsigned int old = atomicSub(&rem[w], 1u);
            if (old == 1u) {                             // last chunk for row w
                const unsigned long long u = atomicAdd(&idxval[w], 0ULL);
                const float an_v = __uint_as_float((unsigned int)u);  // hit or diag
                const float l = an_v - dapw[w] + MARGINF;
                if (l > 0.f)
                    atomicAdd(acc, (unsigned long long)llrint((double)l * SCALEQ));
            }
            __threadfence();
            const unsigned int opd = atomicAdd(pd, 1u);
            if (opd == (unsigned int)npairs - 1u) {      // globally last pair
                __threadfence();
                const unsigned long long s = atomicAdd(acc, 0ULL);
                out[0] = (float)((double)s / SCALEQ / (double)NB);
            }
        }
    }
}

extern "C" void kernel_launch(void* const* d_in, const int* in_sizes, int n_in,
                              void* d_out, int out_size, void* d_ws, size_t ws_size,
                              hipStream_t stream) {
    const float* a = (const float*)d_in[0];
    const float* p = (const float*)d_in[1];
    const float* n = (const float*)d_in[2];
    float* out = (float*)d_out;
    char*  ws  = (char*)d_ws;
    unsigned int*       cnt    = (unsigned int*)ws;
    unsigned int*       pd     = (unsigned int*)(ws + 4);
    unsigned long long* acc    = (unsigned long long*)(ws + 16);
    int*                list   = (int*)(ws + 64);
    float*              dapw   = (float*)(ws + 32832);
    unsigned int*       rem    = (unsigned int*)(ws + 65600);
    unsigned long long* idxval = (unsigned long long*)(ws + 98368);

    init_ws<<<1, 64, 0, stream>>>((unsigned int*)ws);
    triplet_scan<<<NB / 4, 256, 0, stream>>>(a, p, n, cnt, acc, list, dapw, rem, idxval);
    triplet_cols<<<B_GRID, 256, 0, stream>>>(a, n, cnt, pd, acc, list, dapw, rem, idxval, out);
}

// Round 10
// 50.702 us; speedup vs baseline: 3.8820x; 3.8820x over previous
//
#include <hip/hip_runtime.h>

#define NB 8192
#define ND 128
#define MARGINF 0.3f
#define FLTMAX 3.402823466e+38f
#define A_TILES 8             // scan cap: 8 x 16 = 128 cols
#define B_GRID 1024
#define SCALEQ 33554432.0     // 2^25 quantizer -> integer sums, order-independent

// ws layout (bytes):
//   [0]     uint cnt        [16] u64 acc
//   [64]    int   list[8192]
//   [32832] float dapw[8192]
//   [65600] u64   idxval[8192]  (packed (col<<32)|float_bits; col 0xFFFFFFFE = diag)

__device__ __forceinline__ float dot4(float4 x, float4 y) {
    return x.x * y.x + x.y * y.y + x.z * y.z + x.w * y.w;
}

// Butterfly sum within each 32-lane half.
__device__ __forceinline__ float half_reduce(float v) {
    v += __shfl_xor(v, 1, 64);
    v += __shfl_xor(v, 2, 64);
    v += __shfl_xor(v, 4, 64);
    v += __shfl_xor(v, 8, 64);
    v += __shfl_xor(v, 16, 64);
    return v;
}

// Lane owning local column c: col(L) = 2*(L&31) + (L>>5).
__device__ __forceinline__ int owner(int c) {
    return (c & 1) ? 32 + (c >> 1) : (c >> 1);
}

__device__ __forceinline__ int first_col_from_mask(unsigned long long mask) {
    const unsigned int lo = (unsigned int)mask;          // even local cols
    const unsigned int hi = (unsigned int)(mask >> 32);  // odd local cols
    const int ce = lo ? 2 * (__ffs(lo) - 1)     : 0x7fffffff;
    const int co = hi ? 2 * (__ffs(hi) - 1) + 1 : 0x7fffffff;
    return ce < co ? ce : co;
}

__global__ void init_ws(unsigned int* __restrict__ hdr) {
    if (threadIdx.x == 0) {
        hdr[0] = 0u;                              // cnt
        *(unsigned long long*)(hdr + 4) = 0ULL;   // acc (offset 16)
    }
}

// Phase A: one row per wave, scan cols [0,128) in 16-col mini-tiles, early exit.
__global__ __launch_bounds__(256) void triplet_scan(const float* __restrict__ a,
                                                    const float* __restrict__ p,
                                                    const float* __restrict__ n,
                                                    unsigned int* __restrict__ cnt,
                                                    unsigned long long* __restrict__ acc,
                                                    int* __restrict__ list,
                                                    float* __restrict__ dapw,
                                                    unsigned long long* __restrict__ idxval) {
    __shared__ float s_part[4];
    const int tid  = threadIdx.x;
    const int wave = tid >> 6;
    const int lane = tid & 63;
    const int q    = lane & 31;
    const int h    = lane >> 5;
    const int row  = blockIdx.x * 4 + wave;

    const float4 a4 = *(const float4*)(a + (size_t)row * ND + q * 4);
    const float4 p4 = *(const float4*)(p + (size_t)row * ND + q * 4);
    const float dist_ap = half_reduce(dot4(a4, p4));
    const float thresh  = dist_ap + MARGINF;

    float lsum = 0.f;
    bool resolved = false;
    for (int t = 0; t < A_TILES && !resolved; ++t) {
        float myval = FLTMAX;
        #pragma unroll
        for (int k = 0; k < 8; ++k) {
            const int col = t * 16 + 2 * k + h;
            const float4 nv = *(const float4*)(n + (size_t)col * ND + q * 4);
            const float v = half_reduce(dot4(a4, nv));
            if (q == k) myval = v;
        }
        const unsigned long long mask = __ballot(myval < thresh);
        if (mask) {  // wave-uniform
            const int c = first_col_from_mask(mask);
            const float dist_an = __shfl(myval, owner(c), 64);
            const float l = dist_an - dist_ap + MARGINF;
            lsum = l > 0.f ? l : 0.f;
            resolved = true;
        }
    }
    if (!resolved && lane == 0) {                 // relaxed push; read next kernel
        const unsigned int k = atomicAdd(cnt, 1u);
        list[k]   = row;
        dapw[k]   = dist_ap;
        idxval[k] = ~0ULL;
    }
    if (lane == 0) s_part[wave] = lsum;
    __syncthreads();
    if (tid == 0) {
        const double bs = (double)s_part[0] + (double)s_part[1]
                        + (double)s_part[2] + (double)s_part[3];
        if (bs > 0.0) atomicAdd(acc, (unsigned long long)llrint(bs * SCALEQ));
    }
}

// Phase B: (2 worklist rows, 64-col chunk) per wave-iter; each n-chunk load
// serves both rows. Relaxed u64 atomicMin only — no fences, no counters.
__global__ __launch_bounds__(256) void triplet_cols(const float* __restrict__ a,
                                                    const float* __restrict__ n,
                                                    const unsigned int* __restrict__ cnt,
                                                    const int* __restrict__ list,
                                                    const float* __restrict__ dapw,
                                                    unsigned long long* __restrict__ idxval) {
    const int tid  = threadIdx.x;
    const int wave = tid >> 6;
    const int lane = tid & 63;
    const int q    = lane & 31;
    const int h    = lane >> 5;
    const int gw   = blockIdx.x * 4 + wave;
    const int C    = (int)*cnt;
    const int R    = (C + 1) >> 1;                // row-pairs
    const int npairs = R * 128;

    for (int pair = gw; pair < npairs; pair += B_GRID * 4) {
        const int w2 = pair >> 7;                 // row-pair index
        const int tb = (pair & 127) << 6;         // chunk base column
        const int w0 = 2 * w2;
        const int w1 = 2 * w2 + 1;
        const int r0 = list[w0];
        const bool has1 = (w1 < C);
        const int r1 = has1 ? list[w1] : r0;
        const float th0 = dapw[w0] + MARGINF;
        const float th1 = has1 ? dapw[w1] + MARGINF : -FLTMAX;
        const float4 a40 = *(const float4*)(a + (size_t)r0 * ND + q * 4);
        const float4 a41 = *(const float4*)(a + (size_t)r1 * ND + q * 4);

        float my0 = FLTMAX, my1 = FLTMAX;
        #pragma unroll
        for (int k = 0; k < 32; ++k) {
            const int col = tb + 2 * k + h;
            const float4 nv = *(const float4*)(n + (size_t)col * ND + q * 4);
            const float v0 = half_reduce(dot4(a40, nv));   // bit-identical to scan
            const float v1 = half_reduce(dot4(a41, nv));
            if (q == k) { my0 = v0; my1 = v1; }
        }
        // Diagonal fallback candidates (sentinel col, loses to any real hit).
        if (r0 >= tb && r0 < tb + 64) {
            const float dv = __shfl(my0, owner(r0 - tb), 64);
            if (lane == 0) {
                const unsigned long long dkey =
                    (0xFFFFFFFEULL << 32) | (unsigned long long)__float_as_uint(dv);
                atomicMin(&idxval[w0], dkey);
            }
        }
        if (has1 && r1 >= tb && r1 < tb + 64) {
            const float dv = __shfl(my1, owner(r1 - tb), 64);
            if (lane == 0) {
                const unsigned long long dkey =
                    (0xFFFFFFFEULL << 32) | (unsigned long long)__float_as_uint(dv);
                atomicMin(&idxval[w1], dkey);
            }
        }
        const unsigned long long m0 = __ballot(my0 < th0);
        if (m0) {
            const int c = first_col_from_mask(m0);
            const float fv = __shfl(my0, owner(c), 64);
            if (lane == 0) {
                const unsigned long long key =
                    ((unsigned long long)(tb + c) << 32) | (unsigned long long)__float_as_uint(fv);
                atomicMin(&idxval[w0], key);
            }
        }
        const unsigned long long m1 = __ballot(my1 < th1);
        if (m1) {
            const int c = first_col_from_mask(m1);
            const float fv = __shfl(my1, owner(c), 64);
            if (lane == 0) {
                const unsigned long long key =
                    ((unsigned long long)(tb + c) << 32) | (unsigned long long)__float_as_uint(fv);
                atomicMin(&idxval[w1], key);
            }
        }
    }
}

// Finale: 1 block. Integer-quantized per-row losses (order-independent) + tree sum.
__global__ __launch_bounds__(256) void finale(const unsigned int* __restrict__ cnt,
                                              const unsigned long long* __restrict__ acc,
                                              const float* __restrict__ dapw,
                                              const unsigned long long* __restrict__ idxval,
                                              float* __restrict__ out) {
    __shared__ long long s[256];
    const int tid = threadIdx.x;
    const int C   = (int)*cnt;
    long long mysum = 0;
    for (int w = tid; w < C; w += 256) {
        const unsigned long long u = idxval[w];            // hit or diag key
        const float an_v = __uint_as_float((unsigned int)u);
        const float l = an_v - dapw[w] + MARGINF;
        if (l > 0.f) mysum += llrint((double)l * SCALEQ);
    }
    s[tid] = mysum;
    __syncthreads();
    #pragma unroll
    for (int off = 128; off; off >>= 1) {
        if (tid < off) s[tid] += s[tid + off];
        __syncthreads();
    }
    if (tid == 0) {
        const long long total = s[0] + (long long)*acc;
        out[0] = (float)((double)total / SCALEQ / (double)NB);
    }
}

extern "C" void kernel_launch(void* const* d_in, const int* in_sizes, int n_in,
                              void* d_out, int out_size, void* d_ws, size_t ws_size,
                              hipStream_t stream) {
    const float* a = (const float*)d_in[0];
    const float* p = (const float*)d_in[1];
    const float* n = (const float*)d_in[2];
    float* out = (float*)d_out;
    char*  ws  = (char*)d_ws;
    unsigned int*       cnt    = (unsigned int*)ws;
    unsigned long long* acc    = (unsigned long long*)(ws + 16);
    int*                list   = (int*)(ws + 64);
    float*              dapw   = (float*)(ws + 32832);
    unsigned long long* idxval = (unsigned long long*)(ws + 65600);

    init_ws<<<1, 64, 0, stream>>>((unsigned int*)ws);
    triplet_scan<<<NB / 4, 256, 0, stream>>>(a, p, n, cnt, acc, list, dapw, idxval);
    triplet_cols<<<B_GRID, 256, 0, stream>>>(a, n, cnt, list, dapw, idxval);
    finale<<<1, 256, 0, stream>>>(cnt, acc, dapw, idxval, out);
}